// Round 9
// baseline (197.137 us; speedup 1.0000x reference)
//
#include <hip/hip_runtime.h>

// GAT layer on MI355X. N=50000, E=800000 (+N self loops), DIN=256, DOUT=128, H=8.
//
//  r14: r13 showed agg is bound by random-gather L2 misses (2x occupancy ->
//  0 speedup; FETCH 108MB = 8 XCDs re-fetching the whole 12.8MB hbf table).
//  Split agg by head and pin head->XCD via bid%8 (default round-robin
//  dispatch): per-head table hT[h][node][16] = 1.6MB, L2-RESIDENT per XCD.
//  Scores stored head-major (a_srcT[h][node]) for the same reason. GEMM
//  epilogue writes hT directly (MFMA tile index == head).
//
//  K1 conv_w      : W_bf = bf16(W_trans); zeroes per-bucket counters
//  K2 bp          : bucket_pass, 391 buckets of 128 dst nodes, full occupancy
//                   (packed u32 = src<<8 | dst&127)
//  K3 gemm        : hT = bf16(x @ W^T) head-major, 16x16x32 MFMA, W staged in
//                   64KiB LDS in fragment order
//  K4 node_scores : a_srcT/a_dstT[h][v] from hT, grid (v-blocks, 8 heads)
//  K5 agg         : block (bucket,head): slist build + 4-lane group per dst,
//                   register accumulators over 16 cols, self-loop epilogue

constexpr int DIN  = 256;
constexpr int DOUT = 128;
constexpr int H    = 8;
constexpr int BKT  = 128;   // dst nodes per bp bucket
constexpr int CAP  = 2560;  // pair_buf slots per bucket (mean 2048, +11 sigma)
constexpr int CHUNK = 2048; // edges per bucket_pass block
constexpr int MAXNB = 512;  // static LDS sizing for bp hist (nb=391 actual)

typedef __attribute__((ext_vector_type(8))) short bf16x8;
typedef __attribute__((ext_vector_type(4))) float f32x4;

__device__ __forceinline__ float lrelu(float s) { return s >= 0.0f ? s : 0.2f * s; }

__device__ __forceinline__ unsigned short f2bf(float f) {  // RNE
  unsigned u = __float_as_uint(f);
  u += 0x7FFF + ((u >> 16) & 1);
  return (unsigned short)(u >> 16);
}
__device__ __forceinline__ float bflo(unsigned u) { return __uint_as_float(u << 16); }
__device__ __forceinline__ float bfhi(unsigned u) { return __uint_as_float(u & 0xFFFF0000u); }

__device__ __forceinline__ int wave_incl_scan(int v, int lane) {
#pragma unroll
  for (int d = 1; d < 64; d <<= 1) {
    int t = __shfl_up(v, d, 64);
    if (lane >= d) v += t;
  }
  return v;
}

// ---------------- K1: W -> bf16 (+ zero bucket counters) ----------------
__global__ void conv_w(const float* __restrict__ W, unsigned short* __restrict__ Wbf,
                       int n, int* __restrict__ bcount, int nb) {
  int i = blockIdx.x * blockDim.x + threadIdx.x;
  if (i < n) Wbf[i] = f2bf(W[i]);
  if (i < nb) bcount[i] = 0;
}

// ---------------- K2: bucket_pass (128-node buckets) ----------------
__global__ __launch_bounds__(256) void bp(const int* __restrict__ ei,
                                          int* __restrict__ bcount,
                                          unsigned* __restrict__ pair_buf,
                                          int E, int nb) {
  __shared__ int hist[MAXNB];
  __shared__ int gbase[MAXNB];
  int c0 = blockIdx.x * CHUNK;
  for (int i = threadIdx.x; i < nb; i += 256) hist[i] = 0;
  __syncthreads();
  int dcache[8];
#pragma unroll
  for (int q = 0; q < 8; ++q) {
    int e = c0 + q * 256 + threadIdx.x;
    dcache[q] = (e < E) ? ei[E + e] : -1;
    if (dcache[q] >= 0) atomicAdd(&hist[dcache[q] >> 7], 1);
  }
  __syncthreads();
  for (int i = threadIdx.x; i < nb; i += 256) {
    int c = hist[i];
    gbase[i] = c ? atomicAdd(&bcount[i], c) : 0;
  }
  __syncthreads();
  for (int i = threadIdx.x; i < nb; i += 256) hist[i] = 0;  // reuse as rank cursor
  __syncthreads();
  int scache[8];
#pragma unroll
  for (int q = 0; q < 8; ++q) {  // prefetch src indices (independent loads)
    int e = c0 + q * 256 + threadIdx.x;
    scache[q] = (dcache[q] >= 0) ? ei[e] : 0;
  }
#pragma unroll
  for (int q = 0; q < 8; ++q) {
    if (dcache[q] >= 0) {
      int bk = dcache[q] >> 7;
      int r = atomicAdd(&hist[bk], 1);
      pair_buf[bk * CAP + gbase[bk] + r] =
          ((unsigned)scache[q] << 8) | (unsigned)(dcache[q] & 127);
    }
  }
}

// ---------------- K3: GEMM (head-major output) ----------------
// wave: 32 rows x 128 cols. A-frag lane(mr,kg) holds A[m0+mt*16+mr][ks*32+kg*8..+8);
// C/D: tile t = head, col-in-head = mr; row = m0+mt*16+kg*4+r.
// Stores hT[t][row][mr] (head-major, 16 bf16 per node per head).
__global__ __launch_bounds__(256, 2) void gemm(const float* __restrict__ x,
                                               const unsigned short* __restrict__ Wbf,
                                               unsigned short* __restrict__ hT,
                                               int N) {
  __shared__ __align__(16) unsigned short Wlds[DOUT * DIN];  // 64 KiB
  // Stage W in fragment order: chunk c = (t*8+ks)*64 + L holds
  // Wbf[(t*16 + (L&15))*DIN + ks*32 + (L>>4)*8 .. +8).
  {
    const int tid = threadIdx.x;
#pragma unroll
    for (int i = 0; i < 16; ++i) {
      int c = i * 256 + tid;                 // chunk 0..4095
      int t = c >> 9, ks = (c >> 6) & 7, L = c & 63;
      const unsigned short* gp = Wbf + ((t * 16 + (L & 15)) * DIN + ks * 32 + (L >> 4) * 8);
      *(bf16x8*)&Wlds[c * 8] = *(const bf16x8*)gp;
    }
  }
  __syncthreads();
  int wid = blockIdx.x * 4 + (threadIdx.x >> 6);
  int m0 = wid * 32;
  if (m0 >= N) return;
  int lane = threadIdx.x & 63;
  int mr = lane & 15, kg = lane >> 4;
  int r0 = m0 + mr;       if (r0 >= N) r0 = N - 1;  // clamp (stores guarded)
  int r1 = m0 + 16 + mr;  if (r1 >= N) r1 = N - 1;
  const float* xr0 = x + (size_t)r0 * DIN + kg * 8;
  const float* xr1 = x + (size_t)r1 * DIN + kg * 8;
  const unsigned short* fb = Wlds + lane * 8;  // lane's fragment base

  f32x4 acc[2][8];
#pragma unroll
  for (int mt = 0; mt < 2; ++mt)
#pragma unroll
    for (int t = 0; t < 8; ++t) acc[mt][t] = (f32x4){0.f, 0.f, 0.f, 0.f};

  float4 p00 = *(const float4*)xr0, p01 = *(const float4*)(xr0 + 4);
  float4 p10 = *(const float4*)xr1, p11 = *(const float4*)(xr1 + 4);
#pragma unroll
  for (int ks = 0; ks < 8; ++ks) {
    bf16x8 a0, a1;
    a0[0] = (short)f2bf(p00.x); a0[1] = (short)f2bf(p00.y);
    a0[2] = (short)f2bf(p00.z); a0[3] = (short)f2bf(p00.w);
    a0[4] = (short)f2bf(p01.x); a0[5] = (short)f2bf(p01.y);
    a0[6] = (short)f2bf(p01.z); a0[7] = (short)f2bf(p01.w);
    a1[0] = (short)f2bf(p10.x); a1[1] = (short)f2bf(p10.y);
    a1[2] = (short)f2bf(p10.z); a1[3] = (short)f2bf(p10.w);
    a1[4] = (short)f2bf(p11.x); a1[5] = (short)f2bf(p11.y);
    a1[6] = (short)f2bf(p11.z); a1[7] = (short)f2bf(p11.w);
    if (ks < 7) {  // prefetch next ks while MFMAs run
      p00 = *(const float4*)(xr0 + (ks + 1) * 32);
      p01 = *(const float4*)(xr0 + (ks + 1) * 32 + 4);
      p10 = *(const float4*)(xr1 + (ks + 1) * 32);
      p11 = *(const float4*)(xr1 + (ks + 1) * 32 + 4);
    }
#pragma unroll
    for (int t = 0; t < 8; ++t) {
      bf16x8 b = *(const bf16x8*)(fb + ((t * 8 + ks) << 9));  // imm offset
      acc[0][t] = __builtin_amdgcn_mfma_f32_16x16x32_bf16(a0, b, acc[0][t], 0, 0, 0);
      acc[1][t] = __builtin_amdgcn_mfma_f32_16x16x32_bf16(a1, b, acc[1][t], 0, 0, 0);
    }
  }
#pragma unroll
  for (int mt = 0; mt < 2; ++mt)
#pragma unroll
    for (int t = 0; t < 8; ++t)
#pragma unroll
      for (int r = 0; r < 4; ++r) {
        int row = m0 + mt * 16 + kg * 4 + r;
        if (row < N) hT[(size_t)t * N * 16 + (size_t)row * 16 + mr] = f2bf(acc[mt][t][r]);
      }
}

// ---------------- K4: node scores (head-major) ----------------
__global__ __launch_bounds__(256) void node_scores(const unsigned short* __restrict__ hT,
                                                   const float* __restrict__ Wa,
                                                   float* __restrict__ a_srcT,
                                                   float* __restrict__ a_dstT,
                                                   int N) {
  int v = blockIdx.x * 256 + threadIdx.x;
  int h = blockIdx.y;
  if (v >= N) return;
  const unsigned short* hp = hT + (size_t)h * N * 16 + (size_t)v * 16;
  uint4 p0 = *(const uint4*)hp;
  uint4 p1 = *(const uint4*)(hp + 8);
  float hv[16];
  hv[0] = bflo(p0.x); hv[1] = bfhi(p0.x); hv[2] = bflo(p0.y); hv[3] = bfhi(p0.y);
  hv[4] = bflo(p0.z); hv[5] = bfhi(p0.z); hv[6] = bflo(p0.w); hv[7] = bfhi(p0.w);
  hv[8] = bflo(p1.x); hv[9] = bfhi(p1.x); hv[10] = bflo(p1.y); hv[11] = bfhi(p1.y);
  hv[12] = bflo(p1.z); hv[13] = bfhi(p1.z); hv[14] = bflo(p1.w); hv[15] = bfhi(p1.w);
  float s1 = 0.f, s2 = 0.f;
#pragma unroll
  for (int d = 0; d < 16; ++d) {
    s1 += hv[d] * Wa[d];
    s2 += hv[d] * Wa[16 + d];
  }
  a_srcT[(size_t)h * N + v] = s1;
  a_dstT[(size_t)h * N + v] = s2;
}

// ---------------- K5: per-(bucket,head) aggregation ----------------
// Block bid: bucket = bid>>3, head = bid&7 (-> XCD bid%8 = head under default
// round-robin dispatch; hT[head] (1.6MB) + a_srcT[head] (200KB) stay
// L2-resident per XCD). Phase 1: slist build (hist/scan/scatter). Phase 2:
// 4-lane group per dst; lane l covers cols [l*4,l*4+4) of the head (uint2
// load); acc[4]+den in registers, 2-edge pipeline, self-loop epilogue.
__global__ __launch_bounds__(512) void agg(const unsigned* __restrict__ pair_buf,
                                           const int* __restrict__ bcount,
                                           const unsigned short* __restrict__ hT,
                                           const float* __restrict__ a_srcT,
                                           const float* __restrict__ a_dstT,
                                           const float* __restrict__ b_att,
                                           float* __restrict__ out, int N) {
  __shared__ int cnt[BKT];
  __shared__ int off[BKT];
  __shared__ int cur[BKT];
  __shared__ int wsum[2];
  __shared__ unsigned short slist[CAP];
  const int t = threadIdx.x;
  const int bkt = blockIdx.x >> 3;
  const int head = blockIdx.x & 7;
  const int v0 = bkt * BKT;
  if (t < BKT) cnt[t] = 0;
  __syncthreads();
  const int cntE = min(bcount[bkt], CAP);
  const unsigned* reg = pair_buf + (size_t)bkt * CAP;
  // phase 1a: histogram
  for (int i = t; i < cntE; i += 512) atomicAdd(&cnt[reg[i] & 127], 1);
  __syncthreads();
  // phase 1b: exclusive scan over 128 counters (2 waves)
  int val = 0, inc = 0;
  if (t < BKT) {
    val = cnt[t];
    inc = wave_incl_scan(val, t & 63);
    if ((t & 63) == 63) wsum[t >> 6] = inc;
  }
  __syncthreads();
  if (t < BKT) {
    int ex = inc - val + ((t >= 64) ? wsum[0] : 0);
    off[t] = ex;
    cur[t] = ex;
  }
  __syncthreads();
  // phase 1c: scatter into LDS list
  for (int i = t; i < cntE; i += 512) {
    unsigned p = reg[i];
    int k = atomicAdd(&cur[p & 127], 1);
    slist[k] = (unsigned short)(p >> 8);
  }
  __syncthreads();
  // phase 2: aggregate. group per dst (128 groups of 4 lanes).
  const float bb = b_att[0];
  const int grp = t >> 2, l = t & 3;
  int v = v0 + grp;
  if (v >= N) return;
  const unsigned short* hTh = hT + (size_t)head * N * 16;
  const float* asT = a_srcT + (size_t)head * N;
  float ad = a_dstT[(size_t)head * N + v] + bb;
  int beg = off[grp], end = cur[grp];
  float c0 = 0, c1 = 0, c2 = 0, c3 = 0, den = 0;
  int sa = (beg < end) ? slist[beg] : 0;
  int sb = (beg + 1 < end) ? slist[beg + 1] : 0;
  for (int j = beg; j < end; j += 2) {
    int sa2 = (j + 2 < end) ? slist[j + 2] : 0;  // prefetch next pair
    int sb2 = (j + 3 < end) ? slist[j + 3] : 0;
    float asa = asT[sa];
    float asb = asT[sb];
    uint2 ua = *(const uint2*)(hTh + (size_t)sa * 16 + l * 4);
    uint2 ub = *(const uint2*)(hTh + (size_t)sb * 16 + l * 4);
    float ea = __expf(lrelu(asa + ad));
    float eb = (j + 1 < end) ? __expf(lrelu(asb + ad)) : 0.f;
    den += ea + eb;
    c0 += ea * bflo(ua.x) + eb * bflo(ub.x);
    c1 += ea * bfhi(ua.x) + eb * bfhi(ub.x);
    c2 += ea * bflo(ua.y) + eb * bflo(ub.y);
    c3 += ea * bfhi(ua.y) + eb * bfhi(ub.y);
    sa = sa2; sb = sb2;
  }
  // self loop + normalize + store (16 cols of this head per dst)
  float es = __expf(lrelu(asT[v] + ad));
  uint2 u = *(const uint2*)(hTh + (size_t)v * 16 + l * 4);
  float inv = 1.0f / (den + es);
  float4 o = make_float4((c0 + es * bflo(u.x)) * inv, (c1 + es * bfhi(u.x)) * inv,
                         (c2 + es * bflo(u.y)) * inv, (c3 + es * bfhi(u.y)) * inv);
  *(float4*)&out[(size_t)v * DOUT + head * 16 + l * 4] = o;
}

extern "C" void kernel_launch(void* const* d_in, const int* in_sizes, int n_in,
                              void* d_out, int out_size, void* d_ws, size_t ws_size,
                              hipStream_t stream) {
  const float* x     = (const float*)d_in[0];
  const float* W     = (const float*)d_in[1];
  const float* Wa    = (const float*)d_in[2];
  const float* b_att = (const float*)d_in[3];
  const int*   ei    = (const int*)d_in[4];
  const int N  = in_sizes[0] / DIN;
  const int E  = in_sizes[4] / 2;
  const int NB = (N + BKT - 1) / BKT;  // 391 buckets of 128 dst nodes
  float* out = (float*)d_out;

  char* p = (char*)d_ws;
  auto take = [&p](size_t bytes) {
    uintptr_t u = ((uintptr_t)p + 15) & ~(uintptr_t)15;
    p = (char*)(u + bytes);
    return (void*)u;
  };
  unsigned short* hT  = (unsigned short*)take((size_t)N * DOUT * 2);
  unsigned short* Wbf = (unsigned short*)take((size_t)DOUT * DIN * 2);
  float* a_srcT       = (float*)take((size_t)N * H * 4);
  float* a_dstT       = (float*)take((size_t)N * H * 4);
  int* bcount         = (int*)take((size_t)NB * 4);
  unsigned* pair_buf  = (unsigned*)take((size_t)NB * CAP * 4);

  dim3 b256(256);
  const int cw_blocks   = (DOUT * DIN + 255) / 256;       // 128 (covers nb zeroing)
  const int bp_blocks   = (E + CHUNK - 1) / CHUNK;        // 391
  const int gemm_blocks = ((N + 31) / 32 + 3) / 4;        // 391 (4 waves x 32 rows)

  conv_w<<<dim3(cw_blocks), b256, 0, stream>>>(W, Wbf, DOUT * DIN, bcount, NB);
  bp<<<dim3(bp_blocks), b256, 0, stream>>>(ei, bcount, pair_buf, E, NB);
  gemm<<<dim3(gemm_blocks), b256, 0, stream>>>(x, Wbf, hT, N);
  node_scores<<<dim3((N + 255) / 256, H), b256, 0, stream>>>(hT, Wa, a_srcT, a_dstT, N);
  agg<<<dim3(NB * H), dim3(512), 0, stream>>>(pair_buf, bcount, hT, a_srcT, a_dstT,
                                              b_att, out, N);
}

// Round 10
// 196.134 us; speedup vs baseline: 1.0051x; 1.0051x over previous
//
#include <hip/hip_runtime.h>

// GAT layer on MI355X. N=50000, E=800000 (+N self loops), DIN=256, DOUT=128, H=8.
//
//  r15: r14 proved head->XCD pinning kills the gather traffic (FETCH 108->20MB)
//  but replicated the slist build 8x (bank conflicts 0.2M->1.8M, agg 46->69us).
//  Split: csr builds each bucket's dst-sorted edge list ONCE (global slist_g,
//  offs_g); agg2 runs per (bucket,head) with the per-head 1.6MB hT table
//  L2-resident (head = bid&7 -> XCD round-robin), staging the prebuilt slist
//  into LDS via coalesced loads. No atomics, no hist in agg2.
//
//  K1 conv_w      : W_bf = bf16(W_trans); zeroes per-bucket counters
//  K2 bp          : bucket_pass, 391 buckets of 128 dst nodes
//                   (packed u32 = src<<8 | dst&127)
//  K3 gemm        : hT = bf16(x @ W^T) head-major, 16x16x32 MFMA, W staged in
//                   64KiB LDS in fragment order
//  K4 node_scores : a_srcT/a_dstT[h][v] from hT, grid (v-blocks, 8 heads)
//  K5 csr         : per bucket: hist+scan+scatter -> slist_g (bucket-local
//                   indices in offs_g[bkt*129..])
//  K6 agg2        : per (bucket,head): stage slist -> LDS, 4-lane group per
//                   dst, register accumulators, self-loop epilogue

constexpr int DIN  = 256;
constexpr int DOUT = 128;
constexpr int H    = 8;
constexpr int BKT  = 128;   // dst nodes per bp bucket
constexpr int CAP  = 2560;  // pair_buf slots per bucket (mean 2048, +11 sigma)
constexpr int CHUNK = 2048; // edges per bucket_pass block
constexpr int MAXNB = 512;  // static LDS sizing for bp hist (nb=391 actual)

typedef __attribute__((ext_vector_type(8))) short bf16x8;
typedef __attribute__((ext_vector_type(4))) float f32x4;

__device__ __forceinline__ float lrelu(float s) { return s >= 0.0f ? s : 0.2f * s; }

__device__ __forceinline__ unsigned short f2bf(float f) {  // RNE
  unsigned u = __float_as_uint(f);
  u += 0x7FFF + ((u >> 16) & 1);
  return (unsigned short)(u >> 16);
}
__device__ __forceinline__ float bflo(unsigned u) { return __uint_as_float(u << 16); }
__device__ __forceinline__ float bfhi(unsigned u) { return __uint_as_float(u & 0xFFFF0000u); }

__device__ __forceinline__ int wave_incl_scan(int v, int lane) {
#pragma unroll
  for (int d = 1; d < 64; d <<= 1) {
    int t = __shfl_up(v, d, 64);
    if (lane >= d) v += t;
  }
  return v;
}

// ---------------- K1: W -> bf16 (+ zero bucket counters) ----------------
__global__ void conv_w(const float* __restrict__ W, unsigned short* __restrict__ Wbf,
                       int n, int* __restrict__ bcount, int nb) {
  int i = blockIdx.x * blockDim.x + threadIdx.x;
  if (i < n) Wbf[i] = f2bf(W[i]);
  if (i < nb) bcount[i] = 0;
}

// ---------------- K2: bucket_pass (128-node buckets) ----------------
__global__ __launch_bounds__(256) void bp(const int* __restrict__ ei,
                                          int* __restrict__ bcount,
                                          unsigned* __restrict__ pair_buf,
                                          int E, int nb) {
  __shared__ int hist[MAXNB];
  __shared__ int gbase[MAXNB];
  int c0 = blockIdx.x * CHUNK;
  for (int i = threadIdx.x; i < nb; i += 256) hist[i] = 0;
  __syncthreads();
  int dcache[8];
#pragma unroll
  for (int q = 0; q < 8; ++q) {
    int e = c0 + q * 256 + threadIdx.x;
    dcache[q] = (e < E) ? ei[E + e] : -1;
    if (dcache[q] >= 0) atomicAdd(&hist[dcache[q] >> 7], 1);
  }
  __syncthreads();
  for (int i = threadIdx.x; i < nb; i += 256) {
    int c = hist[i];
    gbase[i] = c ? atomicAdd(&bcount[i], c) : 0;
  }
  __syncthreads();
  for (int i = threadIdx.x; i < nb; i += 256) hist[i] = 0;  // reuse as rank cursor
  __syncthreads();
  int scache[8];
#pragma unroll
  for (int q = 0; q < 8; ++q) {  // prefetch src indices (independent loads)
    int e = c0 + q * 256 + threadIdx.x;
    scache[q] = (dcache[q] >= 0) ? ei[e] : 0;
  }
#pragma unroll
  for (int q = 0; q < 8; ++q) {
    if (dcache[q] >= 0) {
      int bk = dcache[q] >> 7;
      int r = atomicAdd(&hist[bk], 1);
      pair_buf[bk * CAP + gbase[bk] + r] =
          ((unsigned)scache[q] << 8) | (unsigned)(dcache[q] & 127);
    }
  }
}

// ---------------- K3: GEMM (head-major output) ----------------
// wave: 32 rows x 128 cols. A-frag lane(mr,kg) holds A[m0+mt*16+mr][ks*32+kg*8..+8);
// C/D: tile t = head, col-in-head = mr; row = m0+mt*16+kg*4+r.
// Stores hT[t][row][mr] (head-major, 16 bf16 per node per head).
__global__ __launch_bounds__(256, 2) void gemm(const float* __restrict__ x,
                                               const unsigned short* __restrict__ Wbf,
                                               unsigned short* __restrict__ hT,
                                               int N) {
  __shared__ __align__(16) unsigned short Wlds[DOUT * DIN];  // 64 KiB
  {
    const int tid = threadIdx.x;
#pragma unroll
    for (int i = 0; i < 16; ++i) {
      int c = i * 256 + tid;                 // chunk 0..4095
      int t = c >> 9, ks = (c >> 6) & 7, L = c & 63;
      const unsigned short* gp = Wbf + ((t * 16 + (L & 15)) * DIN + ks * 32 + (L >> 4) * 8);
      *(bf16x8*)&Wlds[c * 8] = *(const bf16x8*)gp;
    }
  }
  __syncthreads();
  int wid = blockIdx.x * 4 + (threadIdx.x >> 6);
  int m0 = wid * 32;
  if (m0 >= N) return;
  int lane = threadIdx.x & 63;
  int mr = lane & 15, kg = lane >> 4;
  int r0 = m0 + mr;       if (r0 >= N) r0 = N - 1;  // clamp (stores guarded)
  int r1 = m0 + 16 + mr;  if (r1 >= N) r1 = N - 1;
  const float* xr0 = x + (size_t)r0 * DIN + kg * 8;
  const float* xr1 = x + (size_t)r1 * DIN + kg * 8;
  const unsigned short* fb = Wlds + lane * 8;  // lane's fragment base

  f32x4 acc[2][8];
#pragma unroll
  for (int mt = 0; mt < 2; ++mt)
#pragma unroll
    for (int t = 0; t < 8; ++t) acc[mt][t] = (f32x4){0.f, 0.f, 0.f, 0.f};

  float4 p00 = *(const float4*)xr0, p01 = *(const float4*)(xr0 + 4);
  float4 p10 = *(const float4*)xr1, p11 = *(const float4*)(xr1 + 4);
#pragma unroll
  for (int ks = 0; ks < 8; ++ks) {
    bf16x8 a0, a1;
    a0[0] = (short)f2bf(p00.x); a0[1] = (short)f2bf(p00.y);
    a0[2] = (short)f2bf(p00.z); a0[3] = (short)f2bf(p00.w);
    a0[4] = (short)f2bf(p01.x); a0[5] = (short)f2bf(p01.y);
    a0[6] = (short)f2bf(p01.z); a0[7] = (short)f2bf(p01.w);
    a1[0] = (short)f2bf(p10.x); a1[1] = (short)f2bf(p10.y);
    a1[2] = (short)f2bf(p10.z); a1[3] = (short)f2bf(p10.w);
    a1[4] = (short)f2bf(p11.x); a1[5] = (short)f2bf(p11.y);
    a1[6] = (short)f2bf(p11.z); a1[7] = (short)f2bf(p11.w);
    if (ks < 7) {  // prefetch next ks while MFMAs run
      p00 = *(const float4*)(xr0 + (ks + 1) * 32);
      p01 = *(const float4*)(xr0 + (ks + 1) * 32 + 4);
      p10 = *(const float4*)(xr1 + (ks + 1) * 32);
      p11 = *(const float4*)(xr1 + (ks + 1) * 32 + 4);
    }
#pragma unroll
    for (int t = 0; t < 8; ++t) {
      bf16x8 b = *(const bf16x8*)(fb + ((t * 8 + ks) << 9));  // imm offset
      acc[0][t] = __builtin_amdgcn_mfma_f32_16x16x32_bf16(a0, b, acc[0][t], 0, 0, 0);
      acc[1][t] = __builtin_amdgcn_mfma_f32_16x16x32_bf16(a1, b, acc[1][t], 0, 0, 0);
    }
  }
#pragma unroll
  for (int mt = 0; mt < 2; ++mt)
#pragma unroll
    for (int t = 0; t < 8; ++t)
#pragma unroll
      for (int r = 0; r < 4; ++r) {
        int row = m0 + mt * 16 + kg * 4 + r;
        if (row < N) hT[(size_t)t * N * 16 + (size_t)row * 16 + mr] = f2bf(acc[mt][t][r]);
      }
}

// ---------------- K4: node scores (head-major) ----------------
__global__ __launch_bounds__(256) void node_scores(const unsigned short* __restrict__ hT,
                                                   const float* __restrict__ Wa,
                                                   float* __restrict__ a_srcT,
                                                   float* __restrict__ a_dstT,
                                                   int N) {
  int v = blockIdx.x * 256 + threadIdx.x;
  int h = blockIdx.y;
  if (v >= N) return;
  const unsigned short* hp = hT + (size_t)h * N * 16 + (size_t)v * 16;
  uint4 p0 = *(const uint4*)hp;
  uint4 p1 = *(const uint4*)(hp + 8);
  float hv[16];
  hv[0] = bflo(p0.x); hv[1] = bfhi(p0.x); hv[2] = bflo(p0.y); hv[3] = bfhi(p0.y);
  hv[4] = bflo(p0.z); hv[5] = bfhi(p0.z); hv[6] = bflo(p0.w); hv[7] = bfhi(p0.w);
  hv[8] = bflo(p1.x); hv[9] = bfhi(p1.x); hv[10] = bflo(p1.y); hv[11] = bfhi(p1.y);
  hv[12] = bflo(p1.z); hv[13] = bfhi(p1.z); hv[14] = bflo(p1.w); hv[15] = bfhi(p1.w);
  float s1 = 0.f, s2 = 0.f;
#pragma unroll
  for (int d = 0; d < 16; ++d) {
    s1 += hv[d] * Wa[d];
    s2 += hv[d] * Wa[16 + d];
  }
  a_srcT[(size_t)h * N + v] = s1;
  a_dstT[(size_t)h * N + v] = s2;
}

// ---------------- K5: CSR build, once per bucket ----------------
// Hist+scan+scatter into LDS slist, then coalesced copy to slist_g[bkt*CAP..].
// offs_g[bkt*129 + d] = start of dst d's segment (bucket-local); [..+128]=total.
__global__ __launch_bounds__(512) void csr(const unsigned* __restrict__ pair_buf,
                                           const int* __restrict__ bcount,
                                           unsigned short* __restrict__ slist_g,
                                           int* __restrict__ offs_g,
                                           int N) {
  __shared__ int cnt[BKT];
  __shared__ int off[BKT];
  __shared__ int cur[BKT];
  __shared__ int wsum[2];
  __shared__ unsigned short slist[CAP];
  const int t = threadIdx.x;
  const int bkt = blockIdx.x;
  if (t < BKT) cnt[t] = 0;
  __syncthreads();
  const int cntE = min(bcount[bkt], CAP);
  const unsigned* reg = pair_buf + (size_t)bkt * CAP;
  for (int i = t; i < cntE; i += 512) atomicAdd(&cnt[reg[i] & 127], 1);
  __syncthreads();
  int val = 0, inc = 0;
  if (t < BKT) {
    val = cnt[t];
    inc = wave_incl_scan(val, t & 63);
    if ((t & 63) == 63) wsum[t >> 6] = inc;
  }
  __syncthreads();
  if (t < BKT) {
    int ex = inc - val + ((t >= 64) ? wsum[0] : 0);
    off[t] = ex;
    cur[t] = ex;
    offs_g[bkt * 129 + t] = ex;
    if (t == BKT - 1) offs_g[bkt * 129 + BKT] = ex + val;  // total
  }
  __syncthreads();
  for (int i = t; i < cntE; i += 512) {
    unsigned p = reg[i];
    int k = atomicAdd(&cur[p & 127], 1);
    slist[k] = (unsigned short)(p >> 8);
  }
  __syncthreads();
  for (int i = t; i < cntE; i += 512) slist_g[(size_t)bkt * CAP + i] = slist[i];
}

// ---------------- K6: per-(bucket,head) aggregation ----------------
// Block bid: bucket = bid>>3, head = bid&7 (-> XCD bid%8 = head under default
// round-robin dispatch; hT[head] (1.6MB) + a_srcT[head] (200KB) L2-resident
// per XCD). Stage the bucket's prebuilt slist into LDS (coalesced), then
// 4-lane group per dst: lane l covers cols [l*4,l*4+4); acc[4]+den in
// registers, 2-edge pipeline, self-loop epilogue. No atomics, no hist.
__global__ __launch_bounds__(512) void agg2(const unsigned short* __restrict__ slist_g,
                                            const int* __restrict__ offs_g,
                                            const unsigned short* __restrict__ hT,
                                            const float* __restrict__ a_srcT,
                                            const float* __restrict__ a_dstT,
                                            const float* __restrict__ b_att,
                                            float* __restrict__ out, int N) {
  __shared__ unsigned short slist[CAP];
  __shared__ int offL[BKT + 1];
  const int t = threadIdx.x;
  const int bkt = blockIdx.x >> 3;
  const int head = blockIdx.x & 7;
  const int v0 = bkt * BKT;
  if (t < BKT + 1) offL[t] = offs_g[bkt * 129 + t];
  __syncthreads();
  const int total = offL[BKT];
  const unsigned short* sg = slist_g + (size_t)bkt * CAP;
  for (int i = t; i < total; i += 512) slist[i] = sg[i];
  __syncthreads();
  const float bb = b_att[0];
  const int grp = t >> 2, l = t & 3;
  int v = v0 + grp;
  if (v >= N) return;
  const unsigned short* hTh = hT + (size_t)head * N * 16;
  const float* asT = a_srcT + (size_t)head * N;
  float ad = a_dstT[(size_t)head * N + v] + bb;
  int beg = offL[grp], end = offL[grp + 1];
  float c0 = 0, c1 = 0, c2 = 0, c3 = 0, den = 0;
  int sa = (beg < end) ? slist[beg] : 0;
  int sb = (beg + 1 < end) ? slist[beg + 1] : 0;
  for (int j = beg; j < end; j += 2) {
    int sa2 = (j + 2 < end) ? slist[j + 2] : 0;  // prefetch next pair
    int sb2 = (j + 3 < end) ? slist[j + 3] : 0;
    float asa = asT[sa];
    float asb = asT[sb];
    uint2 ua = *(const uint2*)(hTh + (size_t)sa * 16 + l * 4);
    uint2 ub = *(const uint2*)(hTh + (size_t)sb * 16 + l * 4);
    float ea = __expf(lrelu(asa + ad));
    float eb = (j + 1 < end) ? __expf(lrelu(asb + ad)) : 0.f;
    den += ea + eb;
    c0 += ea * bflo(ua.x) + eb * bflo(ub.x);
    c1 += ea * bfhi(ua.x) + eb * bfhi(ub.x);
    c2 += ea * bflo(ua.y) + eb * bflo(ub.y);
    c3 += ea * bfhi(ua.y) + eb * bfhi(ub.y);
    sa = sa2; sb = sb2;
  }
  // self loop + normalize + store (16 cols of this head per dst)
  float es = __expf(lrelu(asT[v] + ad));
  uint2 u = *(const uint2*)(hTh + (size_t)v * 16 + l * 4);
  float inv = 1.0f / (den + es);
  float4 o = make_float4((c0 + es * bflo(u.x)) * inv, (c1 + es * bfhi(u.x)) * inv,
                         (c2 + es * bflo(u.y)) * inv, (c3 + es * bfhi(u.y)) * inv);
  *(float4*)&out[(size_t)v * DOUT + head * 16 + l * 4] = o;
}

extern "C" void kernel_launch(void* const* d_in, const int* in_sizes, int n_in,
                              void* d_out, int out_size, void* d_ws, size_t ws_size,
                              hipStream_t stream) {
  const float* x     = (const float*)d_in[0];
  const float* W     = (const float*)d_in[1];
  const float* Wa    = (const float*)d_in[2];
  const float* b_att = (const float*)d_in[3];
  const int*   ei    = (const int*)d_in[4];
  const int N  = in_sizes[0] / DIN;
  const int E  = in_sizes[4] / 2;
  const int NB = (N + BKT - 1) / BKT;  // 391 buckets of 128 dst nodes
  float* out = (float*)d_out;

  char* p = (char*)d_ws;
  auto take = [&p](size_t bytes) {
    uintptr_t u = ((uintptr_t)p + 15) & ~(uintptr_t)15;
    p = (char*)(u + bytes);
    return (void*)u;
  };
  unsigned short* hT  = (unsigned short*)take((size_t)N * DOUT * 2);
  unsigned short* Wbf = (unsigned short*)take((size_t)DOUT * DIN * 2);
  float* a_srcT       = (float*)take((size_t)N * H * 4);
  float* a_dstT       = (float*)take((size_t)N * H * 4);
  int* bcount         = (int*)take((size_t)NB * 4);
  unsigned* pair_buf  = (unsigned*)take((size_t)NB * CAP * 4);
  unsigned short* slist_g = (unsigned short*)take((size_t)NB * CAP * 2);
  int* offs_g         = (int*)take((size_t)NB * 129 * 4);

  dim3 b256(256);
  const int cw_blocks   = (DOUT * DIN + 255) / 256;       // 128 (covers nb zeroing)
  const int bp_blocks   = (E + CHUNK - 1) / CHUNK;        // 391
  const int gemm_blocks = ((N + 31) / 32 + 3) / 4;        // 391 (4 waves x 32 rows)

  conv_w<<<dim3(cw_blocks), b256, 0, stream>>>(W, Wbf, DOUT * DIN, bcount, NB);
  bp<<<dim3(bp_blocks), b256, 0, stream>>>(ei, bcount, pair_buf, E, NB);
  gemm<<<dim3(gemm_blocks), b256, 0, stream>>>(x, Wbf, hT, N);
  node_scores<<<dim3((N + 255) / 256, H), b256, 0, stream>>>(hT, Wa, a_srcT, a_dstT, N);
  csr<<<dim3(NB), dim3(512), 0, stream>>>(pair_buf, bcount, slist_g, offs_g, N);
  agg2<<<dim3(NB * H), dim3(512), 0, stream>>>(slist_g, offs_g, hT, a_srcT, a_dstT,
                                               b_att, out, N);
}

// Round 11
// 173.444 us; speedup vs baseline: 1.1366x; 1.1308x over previous
//
#include <hip/hip_runtime.h>

// GAT layer on MI355X. N=50000, E=800000 (+N self loops), DIN=256, DOUT=128, H=8.
//
//  r16: head-split (r14/r15) abandoned -- replicating per-edge-visit overhead
//  8x cost more than the L2-locality saved (65-69us vs 46us un-split).
//  Back to r13's structure; agg inner loop widened from 2 to 4 gather chains
//  per 16-lane group (r13 counters: VALU 34%, BW 37%, occ 44% -> latency
//  bound on chain depth, so double the edges in flight per iteration).
//
//  K1 conv_w : W_bf = bf16(W_trans); zeroes per-bucket counters
//  K2 bp     : bucket_pass, 391 buckets of 128 dst nodes
//              (packed u32 = src<<8 | dst&127)
//  K3 gemm   : h_bf = bf16(x @ W^T), 16x16x32 MFMA, W staged in 64KiB LDS in
//              fragment order; one wave = 32 rows x 128 cols
//  K4 node_scores : a_src/a_dst = h_bf . W_att halves, thread per (v,head)
//  K5 agg    : block per 64-dst half-bucket: LDS hist+scan+scatter -> slist;
//              16-lane group per dst, 4-edge pipeline, register accumulators,
//              self-loop + normalize epilogue

constexpr int DIN  = 256;
constexpr int DOUT = 128;
constexpr int H    = 8;
constexpr int BKT  = 128;   // dst nodes per bp bucket
constexpr int CAP  = 2560;  // pair_buf slots per bucket (mean 2048, +11 sigma)
constexpr int CAPH = 1536;  // slist slots per half-bucket (mean 1024, +16 sigma)
constexpr int CHUNK = 2048; // edges per bucket_pass block
constexpr int MAXNB = 512;  // static LDS sizing for bp hist (nb=391 actual)

typedef __attribute__((ext_vector_type(8))) short bf16x8;
typedef __attribute__((ext_vector_type(4))) float f32x4;

__device__ __forceinline__ float lrelu(float s) { return s >= 0.0f ? s : 0.2f * s; }

__device__ __forceinline__ unsigned short f2bf(float f) {  // RNE
  unsigned u = __float_as_uint(f);
  u += 0x7FFF + ((u >> 16) & 1);
  return (unsigned short)(u >> 16);
}
__device__ __forceinline__ float bflo(unsigned u) { return __uint_as_float(u << 16); }
__device__ __forceinline__ float bfhi(unsigned u) { return __uint_as_float(u & 0xFFFF0000u); }

__device__ __forceinline__ int wave_incl_scan(int v, int lane) {
#pragma unroll
  for (int d = 1; d < 64; d <<= 1) {
    int t = __shfl_up(v, d, 64);
    if (lane >= d) v += t;
  }
  return v;
}

// ---------------- K1: W -> bf16 (+ zero bucket counters) ----------------
__global__ void conv_w(const float* __restrict__ W, unsigned short* __restrict__ Wbf,
                       int n, int* __restrict__ bcount, int nb) {
  int i = blockIdx.x * blockDim.x + threadIdx.x;
  if (i < n) Wbf[i] = f2bf(W[i]);
  if (i < nb) bcount[i] = 0;
}

// ---------------- K2: bucket_pass (128-node buckets) ----------------
__global__ __launch_bounds__(256) void bp(const int* __restrict__ ei,
                                          int* __restrict__ bcount,
                                          unsigned* __restrict__ pair_buf,
                                          int E, int nb) {
  __shared__ int hist[MAXNB];
  __shared__ int gbase[MAXNB];
  int c0 = blockIdx.x * CHUNK;
  for (int i = threadIdx.x; i < nb; i += 256) hist[i] = 0;
  __syncthreads();
  int dcache[8];
#pragma unroll
  for (int q = 0; q < 8; ++q) {
    int e = c0 + q * 256 + threadIdx.x;
    dcache[q] = (e < E) ? ei[E + e] : -1;
    if (dcache[q] >= 0) atomicAdd(&hist[dcache[q] >> 7], 1);
  }
  __syncthreads();
  for (int i = threadIdx.x; i < nb; i += 256) {
    int c = hist[i];
    gbase[i] = c ? atomicAdd(&bcount[i], c) : 0;
  }
  __syncthreads();
  for (int i = threadIdx.x; i < nb; i += 256) hist[i] = 0;  // reuse as rank cursor
  __syncthreads();
  int scache[8];
#pragma unroll
  for (int q = 0; q < 8; ++q) {  // prefetch src indices (independent loads)
    int e = c0 + q * 256 + threadIdx.x;
    scache[q] = (dcache[q] >= 0) ? ei[e] : 0;
  }
#pragma unroll
  for (int q = 0; q < 8; ++q) {
    if (dcache[q] >= 0) {
      int bk = dcache[q] >> 7;
      int r = atomicAdd(&hist[bk], 1);
      pair_buf[bk * CAP + gbase[bk] + r] =
          ((unsigned)scache[q] << 8) | (unsigned)(dcache[q] & 127);
    }
  }
}

// ---------------- K3: GEMM ----------------
// wave: 32 rows x 128 cols. A-frag lane(mr,kg) holds A[m0+mt*16+mr][ks*32+kg*8..+8);
// C/D: col = t*16+mr, row = m0+mt*16+kg*4+r.
// B fragments from LDS (fragment-ordered stage of Wbf, 64 KiB).
__global__ __launch_bounds__(256, 2) void gemm(const float* __restrict__ x,
                                               const unsigned short* __restrict__ Wbf,
                                               unsigned short* __restrict__ hbf,
                                               int N) {
  __shared__ __align__(16) unsigned short Wlds[DOUT * DIN];  // 64 KiB
  {
    const int tid = threadIdx.x;
#pragma unroll
    for (int i = 0; i < 16; ++i) {
      int c = i * 256 + tid;                 // chunk 0..4095
      int t = c >> 9, ks = (c >> 6) & 7, L = c & 63;
      const unsigned short* gp = Wbf + ((t * 16 + (L & 15)) * DIN + ks * 32 + (L >> 4) * 8);
      *(bf16x8*)&Wlds[c * 8] = *(const bf16x8*)gp;
    }
  }
  __syncthreads();
  int wid = blockIdx.x * 4 + (threadIdx.x >> 6);
  int m0 = wid * 32;
  if (m0 >= N) return;
  int lane = threadIdx.x & 63;
  int mr = lane & 15, kg = lane >> 4;
  int r0 = m0 + mr;       if (r0 >= N) r0 = N - 1;  // clamp (stores guarded)
  int r1 = m0 + 16 + mr;  if (r1 >= N) r1 = N - 1;
  const float* xr0 = x + (size_t)r0 * DIN + kg * 8;
  const float* xr1 = x + (size_t)r1 * DIN + kg * 8;
  const unsigned short* fb = Wlds + lane * 8;  // lane's fragment base

  f32x4 acc[2][8];
#pragma unroll
  for (int mt = 0; mt < 2; ++mt)
#pragma unroll
    for (int t = 0; t < 8; ++t) acc[mt][t] = (f32x4){0.f, 0.f, 0.f, 0.f};

  float4 p00 = *(const float4*)xr0, p01 = *(const float4*)(xr0 + 4);
  float4 p10 = *(const float4*)xr1, p11 = *(const float4*)(xr1 + 4);
#pragma unroll
  for (int ks = 0; ks < 8; ++ks) {
    bf16x8 a0, a1;
    a0[0] = (short)f2bf(p00.x); a0[1] = (short)f2bf(p00.y);
    a0[2] = (short)f2bf(p00.z); a0[3] = (short)f2bf(p00.w);
    a0[4] = (short)f2bf(p01.x); a0[5] = (short)f2bf(p01.y);
    a0[6] = (short)f2bf(p01.z); a0[7] = (short)f2bf(p01.w);
    a1[0] = (short)f2bf(p10.x); a1[1] = (short)f2bf(p10.y);
    a1[2] = (short)f2bf(p10.z); a1[3] = (short)f2bf(p10.w);
    a1[4] = (short)f2bf(p11.x); a1[5] = (short)f2bf(p11.y);
    a1[6] = (short)f2bf(p11.z); a1[7] = (short)f2bf(p11.w);
    if (ks < 7) {  // prefetch next ks while MFMAs run
      p00 = *(const float4*)(xr0 + (ks + 1) * 32);
      p01 = *(const float4*)(xr0 + (ks + 1) * 32 + 4);
      p10 = *(const float4*)(xr1 + (ks + 1) * 32);
      p11 = *(const float4*)(xr1 + (ks + 1) * 32 + 4);
    }
#pragma unroll
    for (int t = 0; t < 8; ++t) {
      bf16x8 b = *(const bf16x8*)(fb + ((t * 8 + ks) << 9));  // imm offset
      acc[0][t] = __builtin_amdgcn_mfma_f32_16x16x32_bf16(a0, b, acc[0][t], 0, 0, 0);
      acc[1][t] = __builtin_amdgcn_mfma_f32_16x16x32_bf16(a1, b, acc[1][t], 0, 0, 0);
    }
  }
#pragma unroll
  for (int mt = 0; mt < 2; ++mt)
#pragma unroll
    for (int t = 0; t < 8; ++t)
#pragma unroll
      for (int r = 0; r < 4; ++r) {
        int row = m0 + mt * 16 + kg * 4 + r;
        if (row < N) hbf[(size_t)row * DOUT + t * 16 + mr] = f2bf(acc[mt][t][r]);
      }
}

// ---------------- K4: node scores ----------------
__global__ __launch_bounds__(256) void node_scores(const unsigned short* __restrict__ hbf,
                                                   const float* __restrict__ Wa,
                                                   float* __restrict__ a_src,
                                                   float* __restrict__ a_dst,
                                                   int NH) {
  int idx = blockIdx.x * 256 + threadIdx.x;
  if (idx >= NH) return;
  int v = idx >> 3, hh = idx & 7;
  const unsigned short* hp = hbf + (size_t)v * DOUT + hh * 16;
  uint4 p0 = *(const uint4*)hp;
  uint4 p1 = *(const uint4*)(hp + 8);
  float hv[16];
  hv[0] = bflo(p0.x); hv[1] = bfhi(p0.x); hv[2] = bflo(p0.y); hv[3] = bfhi(p0.y);
  hv[4] = bflo(p0.z); hv[5] = bfhi(p0.z); hv[6] = bflo(p0.w); hv[7] = bfhi(p0.w);
  hv[8] = bflo(p1.x); hv[9] = bfhi(p1.x); hv[10] = bflo(p1.y); hv[11] = bfhi(p1.y);
  hv[12] = bflo(p1.z); hv[13] = bfhi(p1.z); hv[14] = bflo(p1.w); hv[15] = bfhi(p1.w);
  float s1 = 0.f, s2 = 0.f;
#pragma unroll
  for (int d = 0; d < 16; ++d) {
    s1 += hv[d] * Wa[d];
    s2 += hv[d] * Wa[16 + d];
  }
  a_src[idx] = s1;
  a_dst[idx] = s2;
}

// ---------------- K5: fused scatter+aggregate, half-bucket blocks ----------
// Block B handles the 64-dst half (B&1) of bucket B>>1. Phase 1: filtered
// hist+scan+scatter of the bucket's edges into LDS slist. Phase 2: 16-lane
// group per dst; lane sl covers cols [sl*8,sl*8+8); head = sl>>1; FOUR gather
// chains in flight per group (r16). den head-private per lane (both lanes of
// a head pair compute the same e -> no cross-lane reduction).
__global__ __launch_bounds__(512) void agg(const unsigned* __restrict__ pair_buf,
                                           const int* __restrict__ bcount,
                                           const unsigned short* __restrict__ hbf,
                                           const float* __restrict__ a_src,
                                           const float* __restrict__ a_dst,
                                           const float* __restrict__ b_att,
                                           float* __restrict__ out, int N) {
  __shared__ int cnt[64];
  __shared__ int off[64];
  __shared__ int cur[64];
  __shared__ unsigned short slist[CAPH];
  const int t = threadIdx.x;
  const int B = blockIdx.x;
  const int bkt = B >> 1;
  const int half = B & 1;
  const int v0 = bkt * BKT + half * 64;
  if (t < 64) cnt[t] = 0;
  __syncthreads();
  const int cntE = min(bcount[bkt], CAP);
  const unsigned* reg = pair_buf + (size_t)bkt * CAP;
  // phase 1a: filtered histogram
  for (int i = t; i < cntE; i += 512) {
    unsigned p = reg[i];
    int d = p & 127;
    if ((d >> 6) == half) atomicAdd(&cnt[d & 63], 1);
  }
  __syncthreads();
  // phase 1b: exclusive scan over 64 counters (one wave)
  if (t < 64) {
    int val = cnt[t];
    int inc = wave_incl_scan(val, t);
    off[t] = inc - val;
    cur[t] = inc - val;
  }
  __syncthreads();
  // phase 1c: filtered scatter into LDS list (reg is L2-hot)
  for (int i = t; i < cntE; i += 512) {
    unsigned p = reg[i];
    int d = p & 127;
    if ((d >> 6) == half) {
      int k = atomicAdd(&cur[d & 63], 1);
      if (k < CAPH) slist[k] = (unsigned short)(p >> 8);
    }
  }
  __syncthreads();
  // phase 2: aggregate, 4 edges in flight. group grp owns dsts {grp, grp+32}.
  const float bb = b_att[0];
  const int grp = t >> 4, sl = t & 15, head = sl >> 1;
  for (int nd = grp; nd < 64; nd += 32) {
    int v = v0 + nd;
    if (v >= N) continue;
    float ad = a_dst[(size_t)v * H + head] + bb;
    int beg = off[nd], end = min(cur[nd], CAPH);
    float a0 = 0, a1 = 0, a2 = 0, a3 = 0, a4 = 0, a5 = 0, a6 = 0, a7 = 0, den = 0;
    for (int j = beg; j < end; j += 4) {
      // 4 independent gather chains (slist -> a_src + hbf row)
      int s0 = slist[j];
      int s1 = (j + 1 < end) ? slist[j + 1] : s0;
      int s2 = (j + 2 < end) ? slist[j + 2] : s0;
      int s3 = (j + 3 < end) ? slist[j + 3] : s0;
      float as0 = a_src[(size_t)s0 * H + head];
      float as1 = a_src[(size_t)s1 * H + head];
      float as2 = a_src[(size_t)s2 * H + head];
      float as3 = a_src[(size_t)s3 * H + head];
      uint4 u0 = *(const uint4*)(hbf + (size_t)s0 * DOUT + sl * 8);
      uint4 u1 = *(const uint4*)(hbf + (size_t)s1 * DOUT + sl * 8);
      uint4 u2 = *(const uint4*)(hbf + (size_t)s2 * DOUT + sl * 8);
      uint4 u3 = *(const uint4*)(hbf + (size_t)s3 * DOUT + sl * 8);
      float e0 = __expf(lrelu(as0 + ad));
      float e1 = (j + 1 < end) ? __expf(lrelu(as1 + ad)) : 0.f;
      float e2 = (j + 2 < end) ? __expf(lrelu(as2 + ad)) : 0.f;
      float e3 = (j + 3 < end) ? __expf(lrelu(as3 + ad)) : 0.f;
      den += (e0 + e1) + (e2 + e3);
      a0 += e0 * bflo(u0.x) + e1 * bflo(u1.x) + e2 * bflo(u2.x) + e3 * bflo(u3.x);
      a1 += e0 * bfhi(u0.x) + e1 * bfhi(u1.x) + e2 * bfhi(u2.x) + e3 * bfhi(u3.x);
      a2 += e0 * bflo(u0.y) + e1 * bflo(u1.y) + e2 * bflo(u2.y) + e3 * bflo(u3.y);
      a3 += e0 * bfhi(u0.y) + e1 * bfhi(u1.y) + e2 * bfhi(u2.y) + e3 * bfhi(u3.y);
      a4 += e0 * bflo(u0.z) + e1 * bflo(u1.z) + e2 * bflo(u2.z) + e3 * bflo(u3.z);
      a5 += e0 * bfhi(u0.z) + e1 * bfhi(u1.z) + e2 * bfhi(u2.z) + e3 * bfhi(u3.z);
      a6 += e0 * bflo(u0.w) + e1 * bflo(u1.w) + e2 * bflo(u2.w) + e3 * bflo(u3.w);
      a7 += e0 * bfhi(u0.w) + e1 * bfhi(u1.w) + e2 * bfhi(u2.w) + e3 * bfhi(u3.w);
    }
    // self loop + normalize + store
    float es = __expf(lrelu(a_src[(size_t)v * H + head] + ad));
    uint4 u = *(const uint4*)(hbf + (size_t)v * DOUT + sl * 8);
    float inv = 1.0f / (den + es);
    float4 o0 = make_float4((a0 + es * bflo(u.x)) * inv, (a1 + es * bfhi(u.x)) * inv,
                            (a2 + es * bflo(u.y)) * inv, (a3 + es * bfhi(u.y)) * inv);
    float4 o1 = make_float4((a4 + es * bflo(u.z)) * inv, (a5 + es * bfhi(u.z)) * inv,
                            (a6 + es * bflo(u.w)) * inv, (a7 + es * bfhi(u.w)) * inv);
    *(float4*)&out[(size_t)v * DOUT + sl * 8] = o0;
    *(float4*)&out[(size_t)v * DOUT + sl * 8 + 4] = o1;
  }
}

extern "C" void kernel_launch(void* const* d_in, const int* in_sizes, int n_in,
                              void* d_out, int out_size, void* d_ws, size_t ws_size,
                              hipStream_t stream) {
  const float* x     = (const float*)d_in[0];
  const float* W     = (const float*)d_in[1];
  const float* Wa    = (const float*)d_in[2];
  const float* b_att = (const float*)d_in[3];
  const int*   ei    = (const int*)d_in[4];
  const int N  = in_sizes[0] / DIN;
  const int E  = in_sizes[4] / 2;
  const int NB = (N + BKT - 1) / BKT;  // 391 buckets of 128 dst nodes
  float* out = (float*)d_out;

  char* p = (char*)d_ws;
  auto take = [&p](size_t bytes) {
    uintptr_t u = ((uintptr_t)p + 15) & ~(uintptr_t)15;
    p = (char*)(u + bytes);
    return (void*)u;
  };
  unsigned short* hbf = (unsigned short*)take((size_t)N * DOUT * 2);
  unsigned short* Wbf = (unsigned short*)take((size_t)DOUT * DIN * 2);
  float* a_src        = (float*)take((size_t)N * H * 4);
  float* a_dst        = (float*)take((size_t)N * H * 4);
  int* bcount         = (int*)take((size_t)NB * 4);
  unsigned* pair_buf  = (unsigned*)take((size_t)NB * CAP * 4);

  dim3 b256(256);
  const int cw_blocks   = (DOUT * DIN + 255) / 256;       // 128 (covers nb zeroing)
  const int bp_blocks   = (E + CHUNK - 1) / CHUNK;        // 391
  const int gemm_blocks = ((N + 31) / 32 + 3) / 4;        // 391 (4 waves x 32 rows)
  const int ns_blocks   = (N * H + 255) / 256;            // 1563

  conv_w<<<dim3(cw_blocks), b256, 0, stream>>>(W, Wbf, DOUT * DIN, bcount, NB);
  bp<<<dim3(bp_blocks), b256, 0, stream>>>(ei, bcount, pair_buf, E, NB);
  gemm<<<dim3(gemm_blocks), b256, 0, stream>>>(x, Wbf, hbf, N);
  node_scores<<<dim3(ns_blocks), b256, 0, stream>>>(hbf, Wa, a_src, a_dst, N * H);
  agg<<<dim3(NB * 2), dim3(512), 0, stream>>>(pair_buf, bcount, hbf, a_src, a_dst,
                                              b_att, out, N);
}